// Round 1
// 1036.428 us; speedup vs baseline: 1.0117x; 1.0117x over previous
//
#include <hip/hip_runtime.h>

#define NN 50000
#define NE 800000
#define NL 3

typedef __bf16 bf16x8 __attribute__((ext_vector_type(8)));
typedef float f32x16 __attribute__((ext_vector_type(16)));
typedef unsigned int u32x4 __attribute__((ext_vector_type(4)));

// ---------------- degree histogram ----------------
__global__ __launch_bounds__(256) void k_deg(const int* __restrict__ trg,
                                             float* __restrict__ deg) {
  int e = blockIdx.x * 256 + threadIdx.x;
  if (e < NE) atomicAdd(&deg[trg[e]], 1.0f);
}

// ---------------- exclusive scan of degrees -> CSR row starts ----------------
__global__ __launch_bounds__(1024) void k_scan(const float* __restrict__ deg,
                                               int* __restrict__ rowstart,
                                               int* __restrict__ cursor) {
  __shared__ int part[1024];
  int t = threadIdx.x;
  int t0 = t * 49, t1 = min(t0 + 49, NN);
  int s = 0;
  for (int i = t0; i < t1; i++) s += (int)deg[i];
  part[t] = s;
  __syncthreads();
  for (int off = 1; off < 1024; off <<= 1) {
    int vv = (t >= off) ? part[t - off] : 0;
    int v = part[t];
    __syncthreads();
    part[t] = v + vv;
    __syncthreads();
  }
  int run = part[t] - s;  // exclusive prefix
  for (int i = t0; i < t1; i++) {
    rowstart[i] = run;
    cursor[i] = run;
    run += (int)deg[i];
  }
  if (t == 1023) rowstart[NN] = NE;
}

// ---------------- CSR fill: bucket src ids by trg ----------------
__global__ __launch_bounds__(256) void k_fill(const int* __restrict__ src,
                                              const int* __restrict__ trg,
                                              int* __restrict__ cursor,
                                              int* __restrict__ csr) {
  int e = blockIdx.x * 256 + threadIdx.x;
  if (e < NE) {
    int pos = atomicAdd(&cursor[trg[e]], 1);
    csr[pos] = src[e];
  }
}

// ---------------- gather aggregation (mean, deg-division folded) ----------------
__global__ __launch_bounds__(256) void k_agg(const float* __restrict__ x,
                                             const int* __restrict__ rowstart,
                                             const int* __restrict__ csr,
                                             float* __restrict__ agg, int relu) {
  int i = blockIdx.x * 256 + threadIdx.x;
  int n = i >> 4, q = i & 15;
  const float4* x4 = (const float4*)x;
  int b = rowstart[n], en = rowstart[n + 1];
  float4 v = make_float4(0.f, 0.f, 0.f, 0.f);
  for (int j = b; j < en; j++) {
    float4 a = x4[(size_t)csr[j] * 16 + q];
    if (relu) {
      a.x = fmaxf(a.x, 0.f); a.y = fmaxf(a.y, 0.f);
      a.z = fmaxf(a.z, 0.f); a.w = fmaxf(a.w, 0.f);
    }
    v.x += a.x; v.y += a.y; v.z += a.z; v.w += a.w;
  }
  float inv = 1.0f / fmaxf((float)(en - b), 1.0f);
  v.x *= inv; v.y *= inv; v.z *= inv; v.w *= inv;
  ((float4*)agg)[(size_t)n * 16 + q] = v;
}

// ---------------- node conv: xout = relu?(x)@Ws + agg@Wn + b ----------------
__global__ __launch_bounds__(256) void k_conv(const float* __restrict__ x,
                                              const float* __restrict__ agg,
                                              const float* __restrict__ Ws,
                                              const float* __restrict__ Wn,
                                              const float* __restrict__ bc,
                                              float* __restrict__ xout, int relu) {
  __shared__ float sWs[64 * 64];
  __shared__ float sWn[64 * 64];
  __shared__ float sx[4][64];
  __shared__ float sa[4][64];
  int tid = threadIdx.x;
  for (int i = tid; i < 4096; i += 256) { sWs[i] = Ws[i]; sWn[i] = Wn[i]; }
  int g = tid >> 6, lane = tid & 63;
  int n = blockIdx.x * 4 + g;
  float xv = x[(size_t)n * 64 + lane];
  if (relu) xv = fmaxf(xv, 0.f);
  sx[g][lane] = xv;
  sa[g][lane] = agg[(size_t)n * 64 + lane];
  __syncthreads();
  float acc = bc[lane];
  #pragma unroll
  for (int k = 0; k < 64; k++) {
    acc += sx[g][k] * sWs[k * 64 + lane] + sa[g][k] * sWn[k * 64 + lane];
  }
  xout[(size_t)n * 64 + lane] = acc;
}

// ---------------- W_fc transpose + bf16 prep: Wt[l][c][k] = bf16(W_fc[l][k][c]) ----------------
__global__ __launch_bounds__(256) void k_wprep(const float* __restrict__ Wfc,
                                               unsigned short* __restrict__ Wt) {
  int idx = blockIdx.x * 256 + threadIdx.x;   // [0, 3*64*256)
  int l = idx >> 14;
  int rem = idx & 16383;
  int c = rem >> 8;
  int k = rem & 255;
  float v = Wfc[((size_t)l * 257 + k) * 64 + c];
  Wt[idx] = __builtin_bit_cast(unsigned short, (__bf16)v);
}

__device__ inline u32x4 pack8(const float* f) {
  u32x4 r;
  #pragma unroll
  for (int i = 0; i < 4; i++) {
    unsigned short lo = __builtin_bit_cast(unsigned short, (__bf16)f[2 * i]);
    unsigned short hi = __builtin_bit_cast(unsigned short, (__bf16)f[2 * i + 1]);
    r[i] = (unsigned)lo | ((unsigned)hi << 16);
  }
  return r;
}

// ---------------- edge update v5: barrier-free, LDS-free, per-wave MFMA ----------------
// One wave owns 32 edges and BOTH 32-col output halves (two 32x32 C-frags).
// MFMA 32x32x16 A-layout is lane-owned (lane&31 = row, lane>>5 = k-half):
// each lane gathers its own edge's ef / x[src] / x[trg] k-half directly to
// registers and converts to bf16 frags in-register. sim = per-lane half-dot
// + one shfl_xor(32); C-row sims broadcast via 16 shfl. No __syncthreads,
// no LDS -> waves stream fully independently (latency-bound fix).
// Inter-layer ef is bf16 (round-at-store == round-at-consumer: bit-identical
// to previous fp32-store + bf16-convert path). Layer 1 updates in place
// (each wave reads exactly the rows it writes; loads dataflow-precede stores).
template <int IN_BF16, int OUT_BF16>
__global__ __launch_bounds__(256, 4) void k_edge(
    const float* __restrict__ x, const int* __restrict__ src,
    const int* __restrict__ trg, const void* ef_in,
    const unsigned short* __restrict__ Wt, const float* __restrict__ w256,
    const float* __restrict__ bfc, void* ef_out) {
  int t = threadIdx.x;
  int w = t >> 6;
  int lane = t & 63;
  int rl = lane & 31;   // edge within tile == MFMA row == output col offset
  int kg = lane >> 5;   // k-half
  int e0 = (blockIdx.x * 4 + w) * 32;
  int e = e0 + rl;

  int se = src[e], te = trg[e];
  const float4* x4 = (const float4*)x;

  // gather this lane's k-half of x[src], x[trg]: 4 chunks of 8 floats at
  // cols j*16 + kg*8  (complementary kg lanes cover the full 256B row)
  float4 sv[8], tv[8];
  #pragma unroll
  for (int j = 0; j < 4; j++) {
    sv[2 * j]     = x4[(size_t)se * 16 + j * 4 + kg * 2];
    sv[2 * j + 1] = x4[(size_t)se * 16 + j * 4 + kg * 2 + 1];
    tv[2 * j]     = x4[(size_t)te * 16 + j * 4 + kg * 2];
    tv[2 * j + 1] = x4[(size_t)te * 16 + j * 4 + kg * 2 + 1];
  }

  u32x4 efr[4];
  if (IN_BF16) {
    // bf16 row = 128B = 8 x u32x4; chunk j at bytes j*32 + kg*16
    const u32x4* eb = (const u32x4*)ef_in;
    #pragma unroll
    for (int j = 0; j < 4; j++) efr[j] = eb[(size_t)e * 8 + j * 2 + kg];
  }

  // sim partials + bf16 frags for xs / xt / |xs-xt|
  float dot = 0.f, n1 = 0.f, n2 = 0.f;
  u32x4 sfr[4], tfr[4], dfr[4];
  #pragma unroll
  for (int j = 0; j < 4; j++) {
    float fs[8], ft[8], fd[8];
    fs[0] = sv[2*j].x; fs[1] = sv[2*j].y; fs[2] = sv[2*j].z; fs[3] = sv[2*j].w;
    fs[4] = sv[2*j+1].x; fs[5] = sv[2*j+1].y; fs[6] = sv[2*j+1].z; fs[7] = sv[2*j+1].w;
    ft[0] = tv[2*j].x; ft[1] = tv[2*j].y; ft[2] = tv[2*j].z; ft[3] = tv[2*j].w;
    ft[4] = tv[2*j+1].x; ft[5] = tv[2*j+1].y; ft[6] = tv[2*j+1].z; ft[7] = tv[2*j+1].w;
    #pragma unroll
    for (int c = 0; c < 8; c++) {
      dot = fmaf(fs[c], ft[c], dot);
      n1 = fmaf(fs[c], fs[c], n1);
      n2 = fmaf(ft[c], ft[c], n2);
      fd[c] = fabsf(fs[c] - ft[c]);
    }
    sfr[j] = pack8(fs);
    tfr[j] = pack8(ft);
    dfr[j] = pack8(fd);
  }

  if (!IN_BF16) {
    // fp32 ef (layer 0): load late so raw x regs are already freed
    const float4* ef4 = (const float4*)ef_in;
    #pragma unroll
    for (int j = 0; j < 4; j++) {
      float4 a = ef4[(size_t)e * 16 + j * 4 + kg * 2];
      float4 b = ef4[(size_t)e * 16 + j * 4 + kg * 2 + 1];
      float f[8] = {a.x, a.y, a.z, a.w, b.x, b.y, b.z, b.w};
      efr[j] = pack8(f);
    }
  }

  // combine kg-halves -> full-row sim in every lane
  dot += __shfl_xor(dot, 32);
  n1 += __shfl_xor(n1, 32);
  n2 += __shfl_xor(n2, 32);
  float sim = dot / fmaxf(sqrtf(n1) * sqrtf(n2), 1e-8f);

  int col0 = rl, col1 = 32 + rl;
  float wv0 = w256[col0], wv1 = w256[col1];
  float b0 = bfc[col0], b1 = bfc[col1];

  // acc init = sim-column (k=256) folded in: acc[r] = sim[C-row]*w256[col] + b
  f32x16 acc0, acc1;
  #pragma unroll
  for (int r = 0; r < 16; r++) {
    int row = (r & 3) + 8 * (r >> 2) + 4 * kg;
    float s = __shfl(sim, row);  // lane 'row' holds edge e0+row's sim
    acc0[r] = fmaf(s, wv0, b0);
    acc1[r] = fmaf(s, wv1, b1);
  }

  // K=256 as 16 MFMA steps x 2 col-halves; B from pre-transposed Wt (L2-hot)
  const u32x4* bq0 = (const u32x4*)(Wt + (size_t)col0 * 256) + kg;
  const u32x4* bq1 = (const u32x4*)(Wt + (size_t)col1 * 256) + kg;
  #pragma unroll
  for (int ks = 0; ks < 16; ks++) {
    u32x4 a = ks < 4 ? efr[ks] : ks < 8 ? sfr[ks - 4]
                     : ks < 12 ? tfr[ks - 8] : dfr[ks - 12];
    bf16x8 av = __builtin_bit_cast(bf16x8, a);
    bf16x8 bv0 = __builtin_bit_cast(bf16x8, bq0[ks * 2]);
    bf16x8 bv1 = __builtin_bit_cast(bf16x8, bq1[ks * 2]);
    acc0 = __builtin_amdgcn_mfma_f32_32x32x16_bf16(av, bv0, acc0, 0, 0, 0);
    acc1 = __builtin_amdgcn_mfma_f32_32x32x16_bf16(av, bv1, acc1, 0, 0, 0);
  }

  // store C (bf16 for inter-layer, fp32 for final)
  #pragma unroll
  for (int r = 0; r < 16; r++) {
    int row = (r & 3) + 8 * (r >> 2) + 4 * kg;
    size_t base = (size_t)(e0 + row) * 64;
    if (OUT_BF16) {
      unsigned short* ob = (unsigned short*)ef_out;
      ob[base + col0] = __builtin_bit_cast(unsigned short, (__bf16)acc0[r]);
      ob[base + col1] = __builtin_bit_cast(unsigned short, (__bf16)acc1[r]);
    } else {
      float* of = (float*)ef_out;
      of[base + col0] = acc0[r];
      of[base + col1] = acc1[r];
    }
  }
}

extern "C" void kernel_launch(void* const* d_in, const int* in_sizes, int n_in,
                              void* d_out, int out_size, void* d_ws, size_t ws_size,
                              hipStream_t stream) {
  const float* x_in   = (const float*)d_in[0];
  const int*   ei     = (const int*)d_in[1];
  const float* ef_in  = (const float*)d_in[2];
  const float* W_self = (const float*)d_in[3];
  const float* W_nbr  = (const float*)d_in[4];
  const float* b_conv = (const float*)d_in[5];
  const float* W_fc   = (const float*)d_in[6];
  const float* b_fc   = (const float*)d_in[7];
  float* out = (float*)d_out;

  const int* src = ei;
  const int* trg = ei + NE;

  char* ws = (char*)d_ws;
  size_t off = 0;
  float* deg      = (float*)(ws + off); off += (((size_t)NN * 4) + 255) & ~(size_t)255;
  int*   rowstart = (int*)(ws + off);   off += (((size_t)(NN + 1) * 4) + 255) & ~(size_t)255;
  int*   cursor   = (int*)(ws + off);   off += (((size_t)NN * 4) + 255) & ~(size_t)255;
  int*   csr      = (int*)(ws + off);   off += (size_t)NE * 4;
  float* agg      = (float*)(ws + off); off += (size_t)NN * 64 * 4;
  float* x_a      = (float*)(ws + off); off += (size_t)NN * 64 * 4;
  float* x_b      = (float*)(ws + off); off += (size_t)NN * 64 * 4;
  unsigned short* Wt  = (unsigned short*)(ws + off); off += (size_t)NL * 64 * 256 * 2;
  unsigned short* efb = (unsigned short*)(ws + off); off += (size_t)NE * 64 * 2;

  hipMemsetAsync(deg, 0, (size_t)NN * 4, stream);
  k_deg<<<(NE + 255) / 256, 256, 0, stream>>>(trg, deg);
  k_scan<<<1, 1024, 0, stream>>>(deg, rowstart, cursor);
  k_fill<<<(NE + 255) / 256, 256, 0, stream>>>(src, trg, cursor, csr);
  k_wprep<<<(NL * 64 * 256) / 256, 256, 0, stream>>>(W_fc, Wt);

  const float* xcur = x_in;
  float* xnext = x_a;

  for (int i = 0; i < NL; i++) {
    int relu = (i > 0) ? 1 : 0;
    k_agg<<<(NN * 16) / 256, 256, 0, stream>>>(xcur, rowstart, csr, agg, relu);
    k_conv<<<NN / 4, 256, 0, stream>>>(xcur, agg,
                                       W_self + (size_t)i * 4096,
                                       W_nbr + (size_t)i * 4096,
                                       b_conv + (size_t)i * 64,
                                       xnext, relu);
    const unsigned short* Wti = Wt + (size_t)i * 64 * 256;
    const float* w256 = W_fc + ((size_t)i * 257 + 256) * 64;
    const float* bfc = b_fc + (size_t)i * 64;
    if (i == 0) {
      k_edge<0, 1><<<NE / 128, 256, 0, stream>>>(xnext, src, trg, ef_in,
                                                 Wti, w256, bfc, efb);
    } else if (i == 1) {
      k_edge<1, 1><<<NE / 128, 256, 0, stream>>>(xnext, src, trg, efb,
                                                 Wti, w256, bfc, efb);
    } else {
      k_edge<1, 0><<<NE / 128, 256, 0, stream>>>(xnext, src, trg, efb,
                                                 Wti, w256, bfc, out);
    }
    xcur = xnext;
    xnext = (xnext == x_a) ? x_b : x_a;
  }
}

// Round 2
// 1017.963 us; speedup vs baseline: 1.0301x; 1.0181x over previous
//
#include <hip/hip_runtime.h>

#define NN 50000
#define NE 800000
#define NL 3

typedef __bf16 bf16x8 __attribute__((ext_vector_type(8)));
typedef float f32x16 __attribute__((ext_vector_type(16)));
typedef unsigned int u32x4 __attribute__((ext_vector_type(4)));

// ---------------- degree histogram ----------------
__global__ __launch_bounds__(256) void k_deg(const int* __restrict__ trg,
                                             float* __restrict__ deg) {
  int e = blockIdx.x * 256 + threadIdx.x;
  if (e < NE) atomicAdd(&deg[trg[e]], 1.0f);
}

// ---------------- exclusive scan of degrees -> CSR row starts ----------------
__global__ __launch_bounds__(1024) void k_scan(const float* __restrict__ deg,
                                               int* __restrict__ rowstart,
                                               int* __restrict__ cursor) {
  __shared__ int part[1024];
  int t = threadIdx.x;
  int t0 = t * 49, t1 = min(t0 + 49, NN);
  int s = 0;
  for (int i = t0; i < t1; i++) s += (int)deg[i];
  part[t] = s;
  __syncthreads();
  for (int off = 1; off < 1024; off <<= 1) {
    int vv = (t >= off) ? part[t - off] : 0;
    int v = part[t];
    __syncthreads();
    part[t] = v + vv;
    __syncthreads();
  }
  int run = part[t] - s;  // exclusive prefix
  for (int i = t0; i < t1; i++) {
    rowstart[i] = run;
    cursor[i] = run;
    run += (int)deg[i];
  }
  if (t == 1023) rowstart[NN] = NE;
}

// ---------------- CSR fill: bucket src ids by trg ----------------
__global__ __launch_bounds__(256) void k_fill(const int* __restrict__ src,
                                              const int* __restrict__ trg,
                                              int* __restrict__ cursor,
                                              int* __restrict__ csr) {
  int e = blockIdx.x * 256 + threadIdx.x;
  if (e < NE) {
    int pos = atomicAdd(&cursor[trg[e]], 1);
    csr[pos] = src[e];
  }
}

// ---------------- gather aggregation (mean, deg-division folded) ----------------
__global__ __launch_bounds__(256) void k_agg(const float* __restrict__ x,
                                             const int* __restrict__ rowstart,
                                             const int* __restrict__ csr,
                                             float* __restrict__ agg, int relu) {
  int i = blockIdx.x * 256 + threadIdx.x;
  int n = i >> 4, q = i & 15;
  const float4* x4 = (const float4*)x;
  int b = rowstart[n], en = rowstart[n + 1];
  float4 v = make_float4(0.f, 0.f, 0.f, 0.f);
  for (int j = b; j < en; j++) {
    float4 a = x4[(size_t)csr[j] * 16 + q];
    if (relu) {
      a.x = fmaxf(a.x, 0.f); a.y = fmaxf(a.y, 0.f);
      a.z = fmaxf(a.z, 0.f); a.w = fmaxf(a.w, 0.f);
    }
    v.x += a.x; v.y += a.y; v.z += a.z; v.w += a.w;
  }
  float inv = 1.0f / fmaxf((float)(en - b), 1.0f);
  v.x *= inv; v.y *= inv; v.z *= inv; v.w *= inv;
  ((float4*)agg)[(size_t)n * 16 + q] = v;
}

// ---------------- node conv: xout = relu?(x)@Ws + agg@Wn + b (+ bf16 mirror) ----------------
__global__ __launch_bounds__(256) void k_conv(const float* __restrict__ x,
                                              const float* __restrict__ agg,
                                              const float* __restrict__ Ws,
                                              const float* __restrict__ Wn,
                                              const float* __restrict__ bc,
                                              float* __restrict__ xout,
                                              unsigned short* __restrict__ xb,
                                              int relu) {
  __shared__ float sWs[64 * 64];
  __shared__ float sWn[64 * 64];
  __shared__ float sx[4][64];
  __shared__ float sa[4][64];
  int tid = threadIdx.x;
  for (int i = tid; i < 4096; i += 256) { sWs[i] = Ws[i]; sWn[i] = Wn[i]; }
  int g = tid >> 6, lane = tid & 63;
  int n = blockIdx.x * 4 + g;
  float xv = x[(size_t)n * 64 + lane];
  if (relu) xv = fmaxf(xv, 0.f);
  sx[g][lane] = xv;
  sa[g][lane] = agg[(size_t)n * 64 + lane];
  __syncthreads();
  float acc = bc[lane];
  #pragma unroll
  for (int k = 0; k < 64; k++) {
    acc += sx[g][k] * sWs[k * 64 + lane] + sa[g][k] * sWn[k * 64 + lane];
  }
  xout[(size_t)n * 64 + lane] = acc;
  xb[(size_t)n * 64 + lane] = __builtin_bit_cast(unsigned short, (__bf16)acc);
}

// ---------------- W_fc transpose + bf16 prep: Wt[l][c][k] = bf16(W_fc[l][k][c]) ----------------
__global__ __launch_bounds__(256) void k_wprep(const float* __restrict__ Wfc,
                                               unsigned short* __restrict__ Wt) {
  int idx = blockIdx.x * 256 + threadIdx.x;   // [0, 3*64*256)
  int l = idx >> 14;
  int rem = idx & 16383;
  int c = rem >> 8;
  int k = rem & 255;
  float v = Wfc[((size_t)l * 257 + k) * 64 + c];
  Wt[idx] = __builtin_bit_cast(unsigned short, (__bf16)v);
}

__device__ inline u32x4 pack8(const float* f) {
  u32x4 r;
  #pragma unroll
  for (int i = 0; i < 4; i++) {
    unsigned short lo = __builtin_bit_cast(unsigned short, (__bf16)f[2 * i]);
    unsigned short hi = __builtin_bit_cast(unsigned short, (__bf16)f[2 * i + 1]);
    r[i] = (unsigned)lo | ((unsigned)hi << 16);
  }
  return r;
}

__device__ inline float bflo(unsigned u) {
  return __builtin_bit_cast(float, u << 16);
}
__device__ inline float bfhi(unsigned u) {
  return __builtin_bit_cast(float, u & 0xffff0000u);
}

// ---------------- edge update v6: bf16 x-mirror + gather-latency overlap ----------------
// One wave owns 32 edges, both 32-col output halves (two 32x32 C-frags),
// no LDS / no barriers. x is gathered from the bf16 mirror xb (128B rows:
// half the bytes AND half the 64B-segment requests of fp32 x); the loaded
// bits ARE the MFMA A-frags for xs/xt. sim is computed from the bf16-rounded
// values (identical to what the MFMA consumes; adds ~1e-3 to sim, ~2e-4 to
// output). acc init = bias only; sim*w256 folded AFTER the MFMA loop so the
// ef-, s-, and t-fragment MFMAs (+ L2-hot Wt loads) execute while the x
// gathers are still in flight (ef issued first, x after -> waiting on ef via
// vmcnt leaves x outstanding).
template <int IN_BF16, int OUT_BF16>
__global__ __launch_bounds__(256, 4) void k_edge(
    const unsigned short* __restrict__ xb, const int* __restrict__ src,
    const int* __restrict__ trg, const void* ef_in,
    const unsigned short* __restrict__ Wt, const float* __restrict__ w256,
    const float* __restrict__ bfc, void* ef_out) {
  int t = threadIdx.x;
  int w = t >> 6;
  int lane = t & 63;
  int rl = lane & 31;   // edge within tile == MFMA row == output col offset
  int kg = lane >> 5;   // k-half
  int e0 = (blockIdx.x * 4 + w) * 32;
  int e = e0 + rl;

  int se = src[e], te = trg[e];

  // ---- issue ef load first (streaming, fast) ----
  u32x4 efr[4];
  if (IN_BF16) {
    const u32x4* eb = (const u32x4*)ef_in;
    #pragma unroll
    for (int j = 0; j < 4; j++) efr[j] = eb[(size_t)e * 8 + j * 2 + kg];
  } else {
    const float4* ef4 = (const float4*)ef_in;
    #pragma unroll
    for (int j = 0; j < 4; j++) {
      float4 a = ef4[(size_t)e * 16 + j * 4 + kg * 2];
      float4 b = ef4[(size_t)e * 16 + j * 4 + kg * 2 + 1];
      float f[8] = {a.x, a.y, a.z, a.w, b.x, b.y, b.z, b.w};
      efr[j] = pack8(f);
    }
  }

  // ---- issue x gathers (slow, random; bf16 rows of 128B) ----
  // lane's k-chunk j: bf16 elements [j*16 + kg*8, +8) == u32x4 idx j*2+kg
  const u32x4* xq = (const u32x4*)xb;
  u32x4 sfr[4], tfr[4];
  #pragma unroll
  for (int j = 0; j < 4; j++) {
    sfr[j] = xq[(size_t)se * 8 + j * 2 + kg];
    tfr[j] = xq[(size_t)te * 8 + j * 2 + kg];
  }

  int col0 = rl, col1 = 32 + rl;
  float wv0 = w256[col0], wv1 = w256[col1];
  f32x16 acc0, acc1;
  {
    float b0 = bfc[col0], b1 = bfc[col1];
    #pragma unroll
    for (int r = 0; r < 16; r++) { acc0[r] = b0; acc1[r] = b1; }
  }

  const u32x4* bq0 = (const u32x4*)(Wt + (size_t)col0 * 256) + kg;
  const u32x4* bq1 = (const u32x4*)(Wt + (size_t)col1 * 256) + kg;

  // ---- ef MFMAs (k 0..63): only need efr + Wt, overlap x-gather latency ----
  #pragma unroll
  for (int ks = 0; ks < 4; ks++) {
    bf16x8 av = __builtin_bit_cast(bf16x8, efr[ks]);
    acc0 = __builtin_amdgcn_mfma_f32_32x32x16_bf16(
        av, __builtin_bit_cast(bf16x8, bq0[ks * 2]), acc0, 0, 0, 0);
    acc1 = __builtin_amdgcn_mfma_f32_32x32x16_bf16(
        av, __builtin_bit_cast(bf16x8, bq1[ks * 2]), acc1, 0, 0, 0);
  }
  // ---- xs MFMAs (k 64..127): need only sfr ----
  #pragma unroll
  for (int ks = 4; ks < 8; ks++) {
    bf16x8 av = __builtin_bit_cast(bf16x8, sfr[ks - 4]);
    acc0 = __builtin_amdgcn_mfma_f32_32x32x16_bf16(
        av, __builtin_bit_cast(bf16x8, bq0[ks * 2]), acc0, 0, 0, 0);
    acc1 = __builtin_amdgcn_mfma_f32_32x32x16_bf16(
        av, __builtin_bit_cast(bf16x8, bq1[ks * 2]), acc1, 0, 0, 0);
  }
  // ---- xt MFMAs (k 128..191) ----
  #pragma unroll
  for (int ks = 8; ks < 12; ks++) {
    bf16x8 av = __builtin_bit_cast(bf16x8, tfr[ks - 8]);
    acc0 = __builtin_amdgcn_mfma_f32_32x32x16_bf16(
        av, __builtin_bit_cast(bf16x8, bq0[ks * 2]), acc0, 0, 0, 0);
    acc1 = __builtin_amdgcn_mfma_f32_32x32x16_bf16(
        av, __builtin_bit_cast(bf16x8, bq1[ks * 2]), acc1, 0, 0, 0);
  }

  // ---- sim partials + |xs-xt| frags (VALU, from bf16-rounded values) ----
  float dot = 0.f, n1 = 0.f, n2 = 0.f;
  u32x4 dfr[4];
  #pragma unroll
  for (int j = 0; j < 4; j++) {
    float fs[8], ft[8], fd[8];
    #pragma unroll
    for (int q = 0; q < 4; q++) {
      fs[2 * q] = bflo(sfr[j][q]); fs[2 * q + 1] = bfhi(sfr[j][q]);
      ft[2 * q] = bflo(tfr[j][q]); ft[2 * q + 1] = bfhi(tfr[j][q]);
    }
    #pragma unroll
    for (int c = 0; c < 8; c++) {
      dot = fmaf(fs[c], ft[c], dot);
      n1 = fmaf(fs[c], fs[c], n1);
      n2 = fmaf(ft[c], ft[c], n2);
      fd[c] = fabsf(fs[c] - ft[c]);
    }
    dfr[j] = pack8(fd);
  }

  // ---- |xs-xt| MFMAs (k 192..255) ----
  #pragma unroll
  for (int ks = 12; ks < 16; ks++) {
    bf16x8 av = __builtin_bit_cast(bf16x8, dfr[ks - 12]);
    acc0 = __builtin_amdgcn_mfma_f32_32x32x16_bf16(
        av, __builtin_bit_cast(bf16x8, bq0[ks * 2]), acc0, 0, 0, 0);
    acc1 = __builtin_amdgcn_mfma_f32_32x32x16_bf16(
        av, __builtin_bit_cast(bf16x8, bq1[ks * 2]), acc1, 0, 0, 0);
  }

  // ---- combine kg-halves -> sim; fold sim-column (k=256) into acc ----
  dot += __shfl_xor(dot, 32);
  n1 += __shfl_xor(n1, 32);
  n2 += __shfl_xor(n2, 32);
  float sim = dot / fmaxf(sqrtf(n1) * sqrtf(n2), 1e-8f);

  // ---- store C (bf16 for inter-layer, fp32 for final) ----
  #pragma unroll
  for (int r = 0; r < 16; r++) {
    int row = (r & 3) + 8 * (r >> 2) + 4 * kg;
    float s = __shfl(sim, row);  // lane 'row' holds edge e0+row's sim
    float o0 = fmaf(s, wv0, acc0[r]);
    float o1 = fmaf(s, wv1, acc1[r]);
    size_t base = (size_t)(e0 + row) * 64;
    if (OUT_BF16) {
      unsigned short* ob = (unsigned short*)ef_out;
      ob[base + col0] = __builtin_bit_cast(unsigned short, (__bf16)o0);
      ob[base + col1] = __builtin_bit_cast(unsigned short, (__bf16)o1);
    } else {
      float* of = (float*)ef_out;
      of[base + col0] = o0;
      of[base + col1] = o1;
    }
  }
}

extern "C" void kernel_launch(void* const* d_in, const int* in_sizes, int n_in,
                              void* d_out, int out_size, void* d_ws, size_t ws_size,
                              hipStream_t stream) {
  const float* x_in   = (const float*)d_in[0];
  const int*   ei     = (const int*)d_in[1];
  const float* ef_in  = (const float*)d_in[2];
  const float* W_self = (const float*)d_in[3];
  const float* W_nbr  = (const float*)d_in[4];
  const float* b_conv = (const float*)d_in[5];
  const float* W_fc   = (const float*)d_in[6];
  const float* b_fc   = (const float*)d_in[7];
  float* out = (float*)d_out;

  const int* src = ei;
  const int* trg = ei + NE;

  char* ws = (char*)d_ws;
  size_t off = 0;
  float* deg      = (float*)(ws + off); off += (((size_t)NN * 4) + 255) & ~(size_t)255;
  int*   rowstart = (int*)(ws + off);   off += (((size_t)(NN + 1) * 4) + 255) & ~(size_t)255;
  int*   cursor   = (int*)(ws + off);   off += (((size_t)NN * 4) + 255) & ~(size_t)255;
  int*   csr      = (int*)(ws + off);   off += (size_t)NE * 4;
  float* agg      = (float*)(ws + off); off += (size_t)NN * 64 * 4;
  float* x_a      = (float*)(ws + off); off += (size_t)NN * 64 * 4;
  float* x_b      = (float*)(ws + off); off += (size_t)NN * 64 * 4;
  unsigned short* Wt  = (unsigned short*)(ws + off); off += (size_t)NL * 64 * 256 * 2;
  unsigned short* efb = (unsigned short*)(ws + off); off += (size_t)NE * 64 * 2;
  unsigned short* xbm = (unsigned short*)(ws + off); off += (size_t)NN * 64 * 2;

  hipMemsetAsync(deg, 0, (size_t)NN * 4, stream);
  k_deg<<<(NE + 255) / 256, 256, 0, stream>>>(trg, deg);
  k_scan<<<1, 1024, 0, stream>>>(deg, rowstart, cursor);
  k_fill<<<(NE + 255) / 256, 256, 0, stream>>>(src, trg, cursor, csr);
  k_wprep<<<(NL * 64 * 256) / 256, 256, 0, stream>>>(W_fc, Wt);

  const float* xcur = x_in;
  float* xnext = x_a;

  for (int i = 0; i < NL; i++) {
    int relu = (i > 0) ? 1 : 0;
    k_agg<<<(NN * 16) / 256, 256, 0, stream>>>(xcur, rowstart, csr, agg, relu);
    k_conv<<<NN / 4, 256, 0, stream>>>(xcur, agg,
                                       W_self + (size_t)i * 4096,
                                       W_nbr + (size_t)i * 4096,
                                       b_conv + (size_t)i * 64,
                                       xnext, xbm, relu);
    const unsigned short* Wti = Wt + (size_t)i * 64 * 256;
    const float* w256 = W_fc + ((size_t)i * 257 + 256) * 64;
    const float* bfc = b_fc + (size_t)i * 64;
    if (i == 0) {
      k_edge<0, 1><<<NE / 128, 256, 0, stream>>>(xbm, src, trg, ef_in,
                                                 Wti, w256, bfc, efb);
    } else if (i == 1) {
      k_edge<1, 1><<<NE / 128, 256, 0, stream>>>(xbm, src, trg, efb,
                                                 Wti, w256, bfc, efb);
    } else {
      k_edge<1, 0><<<NE / 128, 256, 0, stream>>>(xbm, src, trg, efb,
                                                 Wti, w256, bfc, out);
    }
    xcur = xnext;
    xnext = (xnext == x_a) ? x_b : x_a;
  }
}